// Round 8
// baseline (377.661 us; speedup 1.0000x reference)
//
#include <hip/hip_runtime.h>
#include <hip/hip_bf16.h>

#define IN_F 1024
#define OUT_F 1024
#define KTOT (IN_F * 9)   // 9216: channel-major, k = c*1024 + i, c=0 is silu
#define M_ROWS 8192

#define BM 256
#define BN 128
#define BK 64
#define NT (KTOT / BK)    // 144 K-tiles

typedef short bf16x8 __attribute__((ext_vector_type(8)));
typedef int   i32x4  __attribute__((ext_vector_type(4)));
typedef float f32x4  __attribute__((ext_vector_type(4)));

#define AS1 __attribute__((address_space(1)))
#define AS3 __attribute__((address_space(3)))

// ---------------------------------------------------------------- basis eval
__device__ __forceinline__ void kan_basis_fast(
    float xv, const float* __restrict__ g,
    const float* __restrict__ inv1, const float* __restrict__ inv2,
    const float* __restrict__ inv3, float* __restrict__ out) {
  float b[11];
#pragma unroll
  for (int j = 0; j < 11; ++j)
    b[j] = (xv >= g[j] && xv < g[j + 1]) ? 1.0f : 0.0f;
#pragma unroll
  for (int j = 0; j < 10; ++j)
    b[j] = (xv - g[j]) * inv1[j] * b[j] + (g[j + 2] - xv) * inv1[j + 1] * b[j + 1];
#pragma unroll
  for (int j = 0; j < 9; ++j)
    b[j] = (xv - g[j]) * inv2[j] * b[j] + (g[j + 3] - xv) * inv2[j + 1] * b[j + 1];
#pragma unroll
  for (int j = 0; j < 8; ++j)
    b[j] = (xv - g[j]) * inv3[j] * b[j] + (g[j + 4] - xv) * inv3[j + 1] * b[j + 1];
#pragma unroll
  for (int j = 0; j < 8; ++j) out[j] = b[j];
}

// ------------------------------------------------- A expansion (fp32 -> bf16)
__global__ __launch_bounds__(256) void expand_a(
    const float* __restrict__ x, const float* __restrict__ grid,
    __hip_bfloat16* __restrict__ A, int row0, int nrows) {
  int t = blockIdx.x * 256 + threadIdx.x;
  int n = t >> 7;                  // 128 threads per row
  if (n >= nrows) return;
  int i0 = (t & 127) * 8;

  float g[12];
  const float* gp = grid + (size_t)i0 * 12;   // rows identical by construction
#pragma unroll
  for (int j = 0; j < 12; ++j) g[j] = gp[j];
  float inv1[11], inv2[10], inv3[9];
#pragma unroll
  for (int j = 0; j < 11; ++j) inv1[j] = 1.0f / (g[j + 1] - g[j]);
#pragma unroll
  for (int j = 0; j < 10; ++j) inv2[j] = 1.0f / (g[j + 2] - g[j]);
#pragma unroll
  for (int j = 0; j < 9; ++j)  inv3[j] = 1.0f / (g[j + 3] - g[j]);

  const float* xp = x + (size_t)(row0 + n) * IN_F + i0;
  float xs[8];
  *(f32x4*)&xs[0] = *(const f32x4*)xp;
  *(f32x4*)&xs[4] = *(const f32x4*)(xp + 4);

  bf16x8 out[9];
#pragma unroll
  for (int j = 0; j < 8; ++j) {
    float xv = xs[j];
    float bas[8];
    kan_basis_fast(xv, g, inv1, inv2, inv3, bas);
    float s = xv / (1.0f + __expf(-xv));
    out[0][j] = (short)__bfloat16_as_ushort(__float2bfloat16(s));
#pragma unroll
    for (int c = 0; c < 8; ++c)
      out[c + 1][j] = (short)__bfloat16_as_ushort(__float2bfloat16(bas[c]));
  }
  __hip_bfloat16* dst = A + (size_t)n * KTOT + i0;
#pragma unroll
  for (int c = 0; c < 9; ++c)
    *(bf16x8*)(dst + (size_t)c * IN_F) = out[c];
}

// --------------------------------------------------- B packing (fp32 -> bf16)
__global__ __launch_bounds__(256) void pack_b(
    const float* __restrict__ bw, const float* __restrict__ sw,
    const float* __restrict__ sc, __hip_bfloat16* __restrict__ B) {
  int t = blockIdx.x * 256 + threadIdx.x;   // one per (o, i0/8): 1024*128
  if (t >= OUT_F * 128) return;
  int o = t >> 7;
  int i0 = (t & 127) * 8;

  float bwv[8], scv[8];
  const float* bp = bw + (size_t)o * IN_F + i0;
  const float* sp = sc + (size_t)o * IN_F + i0;
  *(f32x4*)&bwv[0] = *(const f32x4*)bp;
  *(f32x4*)&bwv[4] = *(const f32x4*)(bp + 4);
  *(f32x4*)&scv[0] = *(const f32x4*)sp;
  *(f32x4*)&scv[4] = *(const f32x4*)(sp + 4);

  bf16x8 out[9];
#pragma unroll
  for (int j = 0; j < 8; ++j) {
    out[0][j] = (short)__bfloat16_as_ushort(__float2bfloat16(bwv[j]));
    const float* swp = sw + ((size_t)o * IN_F + i0 + j) * 8;
    float swv[8];
    *(f32x4*)&swv[0] = *(const f32x4*)swp;
    *(f32x4*)&swv[4] = *(const f32x4*)(swp + 4);
#pragma unroll
    for (int c = 0; c < 8; ++c)
      out[c + 1][j] = (short)__bfloat16_as_ushort(__float2bfloat16(swv[c] * scv[j]));
  }
  __hip_bfloat16* dst = B + (size_t)o * KTOT + i0;
#pragma unroll
  for (int c = 0; c < 9; ++c)
    *(bf16x8*)(dst + (size_t)c * IN_F) = out[c];
}

// -------------------------------------------------------------- bf16 GEMM BT
// 256x128 tile, BK=64, 8 waves @ 64x64. v8: A-fragments load DIRECTLY from
// global into registers (ping-pong faA/faB, 1 tile ahead; wn-partner waves
// hit L1 on the duplicate read). LDS carries B only (3-slot ring, 48 KB,
// T2 swizzle both-sides, asm ds_read). One barrier/tile. LDS traffic drops
// 176->80 KB/tile (was the binding 1571-cyc floor); MFMA (1242 cyc) becomes
// the constraint. Compiler inserts the exact vmcnt for the C++ A-loads.

__device__ __forceinline__ void gld16(const __hip_bfloat16* g, __hip_bfloat16* l) {
  __builtin_amdgcn_global_load_lds((AS1 void*)g, (AS3 void*)l, 16, 0, 0);
}

// inline-asm LDS read: opaque to alias analysis -> no compiler vmcnt(0) drain
__device__ __forceinline__ bf16x8 dsr128(uint32_t addr) {
  i32x4 r;
  asm volatile("ds_read_b128 %0, %1" : "=v"(r) : "v"(addr));
  return __builtin_bit_cast(bf16x8, r);
}

#define SB __builtin_amdgcn_sched_barrier(0)

#define READ_B(dB, slot, h) do {                                           \
    uint32_t bS_ = bBase + (uint32_t)(slot) * (BN * BK * 2);               \
    _Pragma("unroll")                                                      \
    for (int n_ = 0; n_ < 4; ++n_) dB[n_] = dsr128(bS_ + bOffB[h][n_]);    \
  } while (0)

#define A_LOAD(DST) do {                                                   \
    _Pragma("unroll")                                                      \
    for (int m_ = 0; m_ < 4; ++m_) {                                       \
      DST[m_][0] = *(const bf16x8*)(aPtr[m_]);                             \
      DST[m_][1] = *(const bf16x8*)(aPtr[m_] + 32);                        \
    }                                                                      \
    _Pragma("unroll")                                                      \
    for (int m_ = 0; m_ < 4; ++m_) aPtr[m_] += BK;                         \
  } while (0)

#define MFMA_K(CUR, H, BFR) do {                                           \
    __builtin_amdgcn_s_setprio(1);                                         \
    _Pragma("unroll")                                                      \
    for (int m_ = 0; m_ < 4; ++m_)                                         \
      _Pragma("unroll")                                                    \
      for (int n_ = 0; n_ < 4; ++n_)                                       \
        acc[m_][n_] = __builtin_amdgcn_mfma_f32_16x16x32_bf16(             \
            CUR[m_][H], BFR[n_], acc[m_][n_], 0, 0, 0);                    \
    __builtin_amdgcn_s_setprio(0);                                         \
  } while (0)

#define STAGE_B(slot, koff) do {                                           \
    __hip_bfloat16* bsD_ = &Bs[slot][0];                                   \
    gld16(bSrc[0] + (koff), bsD_ + bDst[0]);                               \
    gld16(bSrc[1] + (koff), bsD_ + bDst[1]);                               \
  } while (0)

// full tile: stage B(t+2), load A(t+1) into NXT, compute tile t from CUR
#define TILE_FULL(CUR, NXT, KT2) do {                                      \
    const int nxt_ = cur == 2 ? 0 : cur + 1;                               \
    const int stg_ = cur == 0 ? 2 : cur - 1;                               \
    READ_B(gb, cur, 1);                                                    \
    STAGE_B(stg_, KT2);                                                    \
    A_LOAD(NXT);                                                           \
    SB;                                                                    \
    asm volatile("s_waitcnt lgkmcnt(4)" ::: "memory"); SB;                 \
    MFMA_K(CUR, 0, fb);  /* compiler vmcnt drains CUR + B-DMA(t+1) */      \
    SB;                                                                    \
    asm volatile("s_waitcnt lgkmcnt(0)" ::: "memory"); SB;                 \
    __builtin_amdgcn_s_barrier(); SB;  /* publish B slot t+1 */            \
    READ_B(fb, nxt_, 0);                                                   \
    SB;                                                                    \
    MFMA_K(CUR, 1, gb);                                                    \
    SB;                                                                    \
    cur = nxt_;                                                            \
  } while (0)

// tile NT-2: no staging; still load A for the last tile
#define TILE_NT2(CUR, NXT) do {                                            \
    const int nxt_ = cur == 2 ? 0 : cur + 1;                               \
    READ_B(gb, cur, 1);                                                    \
    A_LOAD(NXT);                                                           \
    SB;                                                                    \
    asm volatile("s_waitcnt lgkmcnt(4)" ::: "memory"); SB;                 \
    MFMA_K(CUR, 0, fb);                                                    \
    SB;                                                                    \
    asm volatile("s_waitcnt lgkmcnt(0)" ::: "memory"); SB;                 \
    __builtin_amdgcn_s_barrier(); SB;                                      \
    READ_B(fb, nxt_, 0);                                                   \
    SB;                                                                    \
    MFMA_K(CUR, 1, gb);                                                    \
    SB;                                                                    \
    cur = nxt_;                                                            \
  } while (0)

#define TILE_LAST(CUR) do {                                                \
    READ_B(gb, cur, 1);                                                    \
    SB;                                                                    \
    asm volatile("s_waitcnt lgkmcnt(4)" ::: "memory"); SB;                 \
    MFMA_K(CUR, 0, fb);                                                    \
    SB;                                                                    \
    asm volatile("s_waitcnt lgkmcnt(0)" ::: "memory"); SB;                 \
    MFMA_K(CUR, 1, gb);                                                    \
    SB;                                                                    \
  } while (0)

__global__ __launch_bounds__(512, 2) void gemm_v8(
    const __hip_bfloat16* __restrict__ A, const __hip_bfloat16* __restrict__ B,
    float* __restrict__ C) {
  __shared__ __align__(16) __hip_bfloat16 Bs[3][BN * BK];  // 3 x 16 KB

  // T1 bijective XCD swizzle: 8 bn-blocks sharing an A-panel on one XCD
  const int nwg = gridDim.x;            // (M/256)*8, %8 == 0
  const int q = nwg >> 3;
  const int L = (blockIdx.x & 7) * q + (blockIdx.x >> 3);
  const int bm = L >> 3, bn = L & 7;

  const int tid = threadIdx.x;
  const int lane = tid & 63;
  const int wv = tid >> 6;            // 0..7
  const int wm = wv >> 1;             // 0..3 (64-row group)
  const int wn = wv & 1;              // 0..1 (64-col group)
  const int l15 = lane & 15, lhi = lane >> 4;
  const int K = KTOT;

  // ---- B staging: LDS linear, global source pre-swizzled (rule #21).
  const __hip_bfloat16* bSrc[2];
  int bDst[2];
#pragma unroll
  for (int j = 0; j < 2; ++j) {
    int p = j * 512 + wv * 64 + lane;
    int row = p >> 3;
    int col = (p & 7) ^ (row & 7);
    bSrc[j] = B + (size_t)(bn * BN + row) * K + col * 8;
    bDst[j] = (j * 512 + wv * 64) * 8;
  }

  // ---- B fragment read byte-offsets (swizzled), per kk half
  const uint32_t bBase = (uint32_t)(uintptr_t)(AS3 const void*)&Bs[0][0];
  uint32_t bOffB[2][4];
#pragma unroll
  for (int h = 0; h < 2; ++h)
#pragma unroll
    for (int n = 0; n < 4; ++n) {
      int rowB = wn * 64 + n * 16 + l15;
      bOffB[h][n] = (rowB * 64 + (((h * 4 + lhi) ^ (l15 & 7)) * 8)) * 2;
    }

  // ---- A fragment pointers (direct global->reg; MFMA A layout: row=l15,
  // k=lhi*8 within each 32-wide half)
  const __hip_bfloat16* aPtr[4];
#pragma unroll
  for (int m = 0; m < 4; ++m)
    aPtr[m] = A + (size_t)(bm * BM + wm * 64 + m * 16 + l15) * K + lhi * 8;

  f32x4 acc[4][4];
#pragma unroll
  for (int m = 0; m < 4; ++m)
#pragma unroll
    for (int n = 0; n < 4; ++n) acc[m][n] = f32x4{0.f, 0.f, 0.f, 0.f};

  bf16x8 faA[4][2], faB[4][2];   // A frags, ping-pong (tile t / t+1)
  bf16x8 fb[4], gb[4];           // B frags kk0 / kk1

  // ---- prologue: stage B tiles 0,1; load A tile 0; publish slot0
  STAGE_B(0, 0);
  STAGE_B(1, BK);
  A_LOAD(faA);                                        // A(0); aPtr -> 64
  asm volatile("s_waitcnt vmcnt(10)" ::: "memory");   // B slot0 landed
  SB;
  __builtin_amdgcn_s_barrier();
  SB;
  READ_B(fb, 0, 0);                                   // kk0 B(0); 4 lgkm
  SB;

  int cur = 0;
  int kt2 = 2 * BK;
#pragma unroll 1
  for (int tt = 0; tt < (NT - 2) / 2; ++tt) {         // 71 x 2 tiles
    TILE_FULL(faA, faB, kt2); kt2 += BK;
    TILE_FULL(faB, faA, kt2); kt2 += BK;
  }
  TILE_NT2(faA, faB);                                 // t = 142
  TILE_LAST(faB);                                     // t = 143

  // epilogue: C/D mapping col = lane&15, row = (lane>>4)*4 + reg [m89]
#pragma unroll
  for (int m = 0; m < 4; ++m)
#pragma unroll
    for (int n = 0; n < 4; ++n) {
      int col = bn * BN + wn * 64 + n * 16 + l15;
      int row0 = bm * BM + wm * 64 + m * 16 + lhi * 4;
#pragma unroll
      for (int j = 0; j < 4; ++j)
        C[(size_t)(row0 + j) * OUT_F + col] = acc[m][n][j];
    }
}

// ------------------------------------------------ naive fallback (insurance)
__global__ __launch_bounds__(256) void kan_naive(
    const float* __restrict__ x, const float* __restrict__ grid,
    const float* __restrict__ bw, const float* __restrict__ sw,
    const float* __restrict__ sc, float* __restrict__ out) {
  __shared__ float s_act[IN_F];
  __shared__ float s_bas[IN_F * 8];
  int n = blockIdx.x;
  for (int i = threadIdx.x; i < IN_F; i += 256) {
    float xv = x[(size_t)n * IN_F + i];
    float g[12];
    const float* gp = grid + i * 12;
#pragma unroll
    for (int t = 0; t < 12; ++t) g[t] = gp[t];
    float b[11];
#pragma unroll
    for (int j = 0; j < 11; ++j)
      b[j] = (xv >= g[j] && xv < g[j + 1]) ? 1.0f : 0.0f;
#pragma unroll
    for (int k = 1; k <= 3; ++k)
#pragma unroll
      for (int j = 0; j < 11 - k; ++j) {
        float left = (xv - g[j]) / (g[j + k] - g[j]);
        float right = (g[j + k + 1] - xv) / (g[j + k + 1] - g[j + 1]);
        b[j] = left * b[j] + right * b[j + 1];
      }
    s_act[i] = xv / (1.0f + __expf(-xv));
#pragma unroll
    for (int c = 0; c < 8; ++c) s_bas[i * 8 + c] = b[c];
  }
  __syncthreads();
  for (int o = threadIdx.x; o < OUT_F; o += 256) {
    float acc = 0.f;
    const float* bwo = bw + (size_t)o * IN_F;
    const float* swo = sw + (size_t)o * IN_F * 8;
    const float* sco = sc + (size_t)o * IN_F;
    for (int i = 0; i < IN_F; ++i) {
      acc += s_act[i] * bwo[i];
      float p = 0.f;
#pragma unroll
      for (int c = 0; c < 8; ++c) p += s_bas[i * 8 + c] * swo[i * 8 + c];
      acc += p * sco[i];
    }
    out[(size_t)n * OUT_F + o] = acc;
  }
}

// ---------------------------------------------------------------- launch
extern "C" void kernel_launch(void* const* d_in, const int* in_sizes, int n_in,
                              void* d_out, int out_size, void* d_ws, size_t ws_size,
                              hipStream_t stream) {
  const float* x  = (const float*)d_in[0];
  const float* grid = (const float*)d_in[1];
  const float* bw = (const float*)d_in[2];
  const float* sw = (const float*)d_in[3];
  const float* sc = (const float*)d_in[4];
  float* out = (float*)d_out;

  const size_t Bbytes = (size_t)OUT_F * KTOT * 2;   // 18.9 MB
  const size_t rowBytes = (size_t)KTOT * 2;         // 18 KB / A-row

  if (ws_size >= Bbytes + 256 * rowBytes) {
    __hip_bfloat16* Bp = (__hip_bfloat16*)d_ws;
    __hip_bfloat16* Ap = (__hip_bfloat16*)((char*)d_ws + Bbytes);
    size_t arows = (ws_size - Bbytes) / rowBytes;
    int chunk = (int)((arows / 256) * 256);
    if (chunk > M_ROWS) chunk = M_ROWS;

    pack_b<<<OUT_F * 128 / 256, 256, 0, stream>>>(bw, sw, sc, Bp);
    for (int r0 = 0; r0 < M_ROWS; r0 += chunk) {
      int rows = M_ROWS - r0 < chunk ? M_ROWS - r0 : chunk;   // multiple of 256
      expand_a<<<(rows * 128 + 255) / 256, 256, 0, stream>>>(x, grid, Ap, r0, rows);
      gemm_v8<<<(rows / BM) * 8, 512, 0, stream>>>(Ap, Bp, out + (size_t)r0 * OUT_F);
    }
  } else {
    kan_naive<<<M_ROWS, 256, 0, stream>>>(x, grid, bw, sw, sc, out);
  }
}

// Round 9
// 218.557 us; speedup vs baseline: 1.7280x; 1.7280x over previous
//
#include <hip/hip_runtime.h>
#include <hip/hip_bf16.h>

#define IN_F 1024
#define OUT_F 1024
#define KTOT (IN_F * 9)   // 9216: channel-major, k = c*1024 + i, c=0 is silu
#define M_ROWS 8192

#define BM 256
#define BN 128
#define BK 64
#define NT (KTOT / BK)    // 144 K-tiles

typedef short bf16x8 __attribute__((ext_vector_type(8)));
typedef int   i32x4  __attribute__((ext_vector_type(4)));
typedef float f32x4  __attribute__((ext_vector_type(4)));

#define AS1 __attribute__((address_space(1)))
#define AS3 __attribute__((address_space(3)))

// ---------------------------------------------------------------- basis eval
__device__ __forceinline__ void kan_basis_fast(
    float xv, const float* __restrict__ g,
    const float* __restrict__ inv1, const float* __restrict__ inv2,
    const float* __restrict__ inv3, float* __restrict__ out) {
  float b[11];
#pragma unroll
  for (int j = 0; j < 11; ++j)
    b[j] = (xv >= g[j] && xv < g[j + 1]) ? 1.0f : 0.0f;
#pragma unroll
  for (int j = 0; j < 10; ++j)
    b[j] = (xv - g[j]) * inv1[j] * b[j] + (g[j + 2] - xv) * inv1[j + 1] * b[j + 1];
#pragma unroll
  for (int j = 0; j < 9; ++j)
    b[j] = (xv - g[j]) * inv2[j] * b[j] + (g[j + 3] - xv) * inv2[j + 1] * b[j + 1];
#pragma unroll
  for (int j = 0; j < 8; ++j)
    b[j] = (xv - g[j]) * inv3[j] * b[j] + (g[j + 4] - xv) * inv3[j + 1] * b[j + 1];
#pragma unroll
  for (int j = 0; j < 8; ++j) out[j] = b[j];
}

// ------------------------------------------------- A expansion (fp32 -> bf16)
// Writes A in MFMA-FRAGMENT order: fragment (bm,kt,wm,m,kk) = contiguous 1 KB,
// element addr = lane*16B, lane = lhi*16 + l15  (A-operand: row=l15, k=lhi*8+j).
// Thread (l15 = tid&15, lhi = (tid>>4)&3) handles row nb*16+l15, i0 = base+lhi*8
// -> each per-channel wave store is one coalesced 1 KB fragment write.
__global__ __launch_bounds__(256) void expand_a(
    const float* __restrict__ x, const float* __restrict__ grid,
    __hip_bfloat16* __restrict__ A, int row0, int nrows) {
  const int tid = threadIdx.x;
  const int lane = tid & 63;
  const int wvx = tid >> 6;            // 0..3 : i-subblock
  const int l15 = lane & 15;
  const int lhi = lane >> 4;

  const int nb = blockIdx.x >> 3;      // 16-row group (local)
  const int ib = blockIdx.x & 7;       // 128-wide i group
  const int n_l = nb * 16 + l15;       // local row
  const int i0 = ib * 128 + wvx * 32 + lhi * 8;

  const int bm = n_l >> 8, wm = (n_l >> 6) & 3, m = (n_l >> 4) & 3;

  float g[12];
  const float* gp = grid + (size_t)i0 * 12;   // rows identical by construction
#pragma unroll
  for (int j = 0; j < 12; ++j) g[j] = gp[j];
  float inv1[11], inv2[10], inv3[9];
#pragma unroll
  for (int j = 0; j < 11; ++j) inv1[j] = 1.0f / (g[j + 1] - g[j]);
#pragma unroll
  for (int j = 0; j < 10; ++j) inv2[j] = 1.0f / (g[j + 2] - g[j]);
#pragma unroll
  for (int j = 0; j < 9; ++j)  inv3[j] = 1.0f / (g[j + 3] - g[j]);

  const float* xp = x + (size_t)(row0 + n_l) * IN_F + i0;
  float xs[8];
  *(f32x4*)&xs[0] = *(const f32x4*)xp;
  *(f32x4*)&xs[4] = *(const f32x4*)(xp + 4);

  bf16x8 out[9];
#pragma unroll
  for (int j = 0; j < 8; ++j) {
    float xv = xs[j];
    float bas[8];
    kan_basis_fast(xv, g, inv1, inv2, inv3, bas);
    float s = xv / (1.0f + __expf(-xv));
    out[0][j] = (short)__bfloat16_as_ushort(__float2bfloat16(s));
#pragma unroll
    for (int c = 0; c < 8; ++c)
      out[c + 1][j] = (short)__bfloat16_as_ushort(__float2bfloat16(bas[c]));
  }

#pragma unroll
  for (int c = 0; c < 9; ++c) {
    int k0 = c * IN_F + i0;            // 8-aligned; 32-block uniform per wave
    int kt = k0 >> 6;
    int kk = (k0 >> 5) & 1;
    size_t frag = ((((size_t)bm * NT + kt) * 4 + wm) * 4 + m) * 2 + kk;
    *(bf16x8*)(A + frag * 512 + lane * 8) = out[c];
  }
}

// --------------------------------------------------- B packing (fp32 -> bf16)
__global__ __launch_bounds__(256) void pack_b(
    const float* __restrict__ bw, const float* __restrict__ sw,
    const float* __restrict__ sc, __hip_bfloat16* __restrict__ B) {
  int t = blockIdx.x * 256 + threadIdx.x;   // one per (o, i0/8): 1024*128
  if (t >= OUT_F * 128) return;
  int o = t >> 7;
  int i0 = (t & 127) * 8;

  float bwv[8], scv[8];
  const float* bp = bw + (size_t)o * IN_F + i0;
  const float* sp = sc + (size_t)o * IN_F + i0;
  *(f32x4*)&bwv[0] = *(const f32x4*)bp;
  *(f32x4*)&bwv[4] = *(const f32x4*)(bp + 4);
  *(f32x4*)&scv[0] = *(const f32x4*)sp;
  *(f32x4*)&scv[4] = *(const f32x4*)(sp + 4);

  bf16x8 out[9];
#pragma unroll
  for (int j = 0; j < 8; ++j) {
    out[0][j] = (short)__bfloat16_as_ushort(__float2bfloat16(bwv[j]));
    const float* swp = sw + ((size_t)o * IN_F + i0 + j) * 8;
    float swv[8];
    *(f32x4*)&swv[0] = *(const f32x4*)swp;
    *(f32x4*)&swv[4] = *(const f32x4*)(swp + 4);
#pragma unroll
    for (int c = 0; c < 8; ++c)
      out[c + 1][j] = (short)__bfloat16_as_ushort(__float2bfloat16(swv[c] * scv[j]));
  }
  __hip_bfloat16* dst = B + (size_t)o * KTOT + i0;
#pragma unroll
  for (int c = 0; c < 9; ++c)
    *(bf16x8*)(dst + (size_t)c * IN_F) = out[c];
}

// -------------------------------------------------------------- bf16 GEMM BT
// v9: A loads DIRECT from global in fragment order (1 coalesced dwordx4 per
// frag; wn-partner L1-hits the duplicate), ping-pong 1 tile ahead. B keeps
// the proven v7 path: 3-slot LDS ring, T2 swizzle both-sides, asm ds_read,
// counted waits, one barrier/tile. Floors/CU/tile: MFMA 1242 (binding) >
// L1 A-feed ~1024 > LDS-B ~770 (different ports).

__device__ __forceinline__ void gld16(const __hip_bfloat16* g, __hip_bfloat16* l) {
  __builtin_amdgcn_global_load_lds((AS1 void*)g, (AS3 void*)l, 16, 0, 0);
}

// inline-asm LDS read: opaque to alias analysis -> no compiler vmcnt(0) drain
__device__ __forceinline__ bf16x8 dsr128(uint32_t addr) {
  i32x4 r;
  asm volatile("ds_read_b128 %0, %1" : "=v"(r) : "v"(addr));
  return __builtin_bit_cast(bf16x8, r);
}

#define SB __builtin_amdgcn_sched_barrier(0)

#define READ_B(dB, slot, h) do {                                           \
    uint32_t bS_ = bBase + (uint32_t)(slot) * (BN * BK * 2);               \
    _Pragma("unroll")                                                      \
    for (int n_ = 0; n_ < 4; ++n_) dB[n_] = dsr128(bS_ + bOffB[h][n_]);    \
  } while (0)

// A(t+1): 8 coalesced frag loads from the running tile pointer, then advance
#define A_LOAD(DST) do {                                                   \
    _Pragma("unroll")                                                      \
    for (int m_ = 0; m_ < 4; ++m_) {                                       \
      DST[m_][0] = *(const bf16x8*)(aTile + m_ * 1024);                    \
      DST[m_][1] = *(const bf16x8*)(aTile + m_ * 1024 + 512);              \
    }                                                                      \
    aTile += 16384;                                                        \
  } while (0)

#define MFMA_K(CUR, H, BFR) do {                                           \
    __builtin_amdgcn_s_setprio(1);                                         \
    _Pragma("unroll")                                                      \
    for (int m_ = 0; m_ < 4; ++m_)                                         \
      _Pragma("unroll")                                                    \
      for (int n_ = 0; n_ < 4; ++n_)                                       \
        acc[m_][n_] = __builtin_amdgcn_mfma_f32_16x16x32_bf16(             \
            CUR[m_][H], BFR[n_], acc[m_][n_], 0, 0, 0);                    \
    __builtin_amdgcn_s_setprio(0);                                         \
  } while (0)

#define STAGE_B(slot, koff) do {                                           \
    __hip_bfloat16* bsD_ = &Bs[slot][0];                                   \
    gld16(bSrc[0] + (koff), bsD_ + bDst[0]);                               \
    gld16(bSrc[1] + (koff), bsD_ + bDst[1]);                               \
  } while (0)

// steady tile: stage B(t+2), load A(t+1) into NXT, compute tile t from CUR
#define TILE_FULL(CUR, NXT, KT2) do {                                      \
    const int nxt_ = cur == 2 ? 0 : cur + 1;                               \
    const int stg_ = cur == 0 ? 2 : cur - 1;                               \
    READ_B(gb, cur, 1);                  /* lgkm: fb 4 + gb 4 */           \
    STAGE_B(stg_, KT2);                                                    \
    A_LOAD(NXT);                                                           \
    SB;                                                                    \
    asm volatile("s_waitcnt lgkmcnt(4)" ::: "memory"); SB;                 \
    MFMA_K(CUR, 0, fb);   /* compiler vmcnt covers CUR + B-DMA(t+1) */     \
    SB;                                                                    \
    asm volatile("s_waitcnt lgkmcnt(0)" ::: "memory"); SB;                 \
    asm volatile("s_waitcnt vmcnt(10)" ::: "memory"); SB;                  \
    __builtin_amdgcn_s_barrier(); SB;    /* publish B slot t+1 */          \
    READ_B(fb, nxt_, 0);                                                   \
    SB;                                                                    \
    MFMA_K(CUR, 1, gb);                                                    \
    SB;                                                                    \
    cur = nxt_;                                                            \
  } while (0)

#define TILE_NT2(CUR, NXT) do {                                            \
    const int nxt_ = cur == 2 ? 0 : cur + 1;                               \
    READ_B(gb, cur, 1);                                                    \
    A_LOAD(NXT);                                                           \
    SB;                                                                    \
    asm volatile("s_waitcnt lgkmcnt(4)" ::: "memory"); SB;                 \
    MFMA_K(CUR, 0, fb);                                                    \
    SB;                                                                    \
    asm volatile("s_waitcnt lgkmcnt(0)" ::: "memory"); SB;                 \
    asm volatile("s_waitcnt vmcnt(8)" ::: "memory"); SB;                   \
    __builtin_amdgcn_s_barrier(); SB;                                      \
    READ_B(fb, nxt_, 0);                                                   \
    SB;                                                                    \
    MFMA_K(CUR, 1, gb);                                                    \
    SB;                                                                    \
    cur = nxt_;                                                            \
  } while (0)

#define TILE_LAST(CUR) do {                                                \
    READ_B(gb, cur, 1);                                                    \
    SB;                                                                    \
    asm volatile("s_waitcnt lgkmcnt(4)" ::: "memory"); SB;                 \
    MFMA_K(CUR, 0, fb);                                                    \
    SB;                                                                    \
    asm volatile("s_waitcnt lgkmcnt(0)" ::: "memory"); SB;                 \
    MFMA_K(CUR, 1, gb);                                                    \
    SB;                                                                    \
  } while (0)

__global__ __launch_bounds__(512, 2) void gemm_v9(
    const __hip_bfloat16* __restrict__ A, const __hip_bfloat16* __restrict__ B,
    float* __restrict__ C) {
  __shared__ __align__(16) __hip_bfloat16 Bs[3][BN * BK];  // 3 x 16 KB

  // T1 bijective XCD swizzle: 8 bn-blocks sharing an A-panel on one XCD
  const int nwg = gridDim.x;            // (M/256)*8, %8 == 0
  const int q = nwg >> 3;
  const int L = (blockIdx.x & 7) * q + (blockIdx.x >> 3);
  const int bm = L >> 3, bn = L & 7;

  const int tid = threadIdx.x;
  const int lane = tid & 63;
  const int wv = tid >> 6;            // 0..7
  const int wm = wv >> 1;             // 0..3 (64-row group)
  const int wn = wv & 1;              // 0..1 (64-col group)
  const int l15 = lane & 15, lhi = lane >> 4;
  const int K = KTOT;

  // ---- B staging: LDS linear, global source pre-swizzled (rule #21).
  const __hip_bfloat16* bSrc[2];
  int bDst[2];
#pragma unroll
  for (int j = 0; j < 2; ++j) {
    int p = j * 512 + wv * 64 + lane;
    int row = p >> 3;
    int col = (p & 7) ^ (row & 7);
    bSrc[j] = B + (size_t)(bn * BN + row) * K + col * 8;
    bDst[j] = (j * 512 + wv * 64) * 8;
  }

  // ---- B fragment read byte-offsets (swizzled), per kk half
  const uint32_t bBase = (uint32_t)(uintptr_t)(AS3 const void*)&Bs[0][0];
  uint32_t bOffB[2][4];
#pragma unroll
  for (int h = 0; h < 2; ++h)
#pragma unroll
    for (int n = 0; n < 4; ++n) {
      int rowB = wn * 64 + n * 16 + l15;
      bOffB[h][n] = (rowB * 64 + (((h * 4 + lhi) ^ (l15 & 7)) * 8)) * 2;
    }

  // ---- A: fragment-ordered panel; running tile pointer (frag = 1 KB,
  // lane offset = lane*16B; per tile: [wm][m][kk] frags, stride 16384 elems)
  const __hip_bfloat16* aTile =
      A + (size_t)bm * NT * 16384 + wm * 4096 + lane * 8;

  f32x4 acc[4][4];
#pragma unroll
  for (int m = 0; m < 4; ++m)
#pragma unroll
    for (int n = 0; n < 4; ++n) acc[m][n] = f32x4{0.f, 0.f, 0.f, 0.f};

  bf16x8 faA[4][2], faB[4][2];   // A frags ping-pong (tile t / t+1)
  bf16x8 fb[4], gb[4];           // B frags kk0 / kk1

  // ---- prologue: stage B tiles 0,1; load A(0); publish slot0
  STAGE_B(0, 0);                                      // vm 2
  STAGE_B(1, BK);                                     // vm 4
  A_LOAD(faA);                                        // vm 12
  asm volatile("s_waitcnt vmcnt(10)" ::: "memory");   // B slot0 landed
  SB;
  __builtin_amdgcn_s_barrier();
  SB;
  READ_B(fb, 0, 0);                                   // lgkm 4
  SB;

  int cur = 0;
  int kt2 = 2 * BK;
#pragma unroll 1
  for (int tt = 0; tt < (NT - 2) / 2; ++tt) {         // 71 x 2 tiles
    TILE_FULL(faA, faB, kt2); kt2 += BK;
    TILE_FULL(faB, faA, kt2); kt2 += BK;
  }
  TILE_NT2(faA, faB);                                 // t = 142
  TILE_LAST(faB);                                     // t = 143

  // epilogue: C/D mapping col = lane&15, row = (lane>>4)*4 + reg [m89]
#pragma unroll
  for (int m = 0; m < 4; ++m)
#pragma unroll
    for (int n = 0; n < 4; ++n) {
      int col = bn * BN + wn * 64 + n * 16 + l15;
      int row0 = bm * BM + wm * 64 + m * 16 + lhi * 4;
#pragma unroll
      for (int j = 0; j < 4; ++j)
        C[(size_t)(row0 + j) * OUT_F + col] = acc[m][n][j];
    }
}

// ------------------------------------------------ naive fallback (insurance)
__global__ __launch_bounds__(256) void kan_naive(
    const float* __restrict__ x, const float* __restrict__ grid,
    const float* __restrict__ bw, const float* __restrict__ sw,
    const float* __restrict__ sc, float* __restrict__ out) {
  __shared__ float s_act[IN_F];
  __shared__ float s_bas[IN_F * 8];
  int n = blockIdx.x;
  for (int i = threadIdx.x; i < IN_F; i += 256) {
    float xv = x[(size_t)n * IN_F + i];
    float g[12];
    const float* gp = grid + i * 12;
#pragma unroll
    for (int t = 0; t < 12; ++t) g[t] = gp[t];
    float b[11];
#pragma unroll
    for (int j = 0; j < 11; ++j)
      b[j] = (xv >= g[j] && xv < g[j + 1]) ? 1.0f : 0.0f;
#pragma unroll
    for (int k = 1; k <= 3; ++k)
#pragma unroll
      for (int j = 0; j < 11 - k; ++j) {
        float left = (xv - g[j]) / (g[j + k] - g[j]);
        float right = (g[j + k + 1] - xv) / (g[j + k + 1] - g[j + 1]);
        b[j] = left * b[j] + right * b[j + 1];
      }
    s_act[i] = xv / (1.0f + __expf(-xv));
#pragma unroll
    for (int c = 0; c < 8; ++c) s_bas[i * 8 + c] = b[c];
  }
  __syncthreads();
  for (int o = threadIdx.x; o < OUT_F; o += 256) {
    float acc = 0.f;
    const float* bwo = bw + (size_t)o * IN_F;
    const float* swo = sw + (size_t)o * IN_F * 8;
    const float* sco = sc + (size_t)o * IN_F;
    for (int i = 0; i < IN_F; ++i) {
      acc += s_act[i] * bwo[i];
      float p = 0.f;
#pragma unroll
      for (int c = 0; c < 8; ++c) p += s_bas[i * 8 + c] * swo[i * 8 + c];
      acc += p * sco[i];
    }
    out[(size_t)n * OUT_F + o] = acc;
  }
}

// ---------------------------------------------------------------- launch
extern "C" void kernel_launch(void* const* d_in, const int* in_sizes, int n_in,
                              void* d_out, int out_size, void* d_ws, size_t ws_size,
                              hipStream_t stream) {
  const float* x  = (const float*)d_in[0];
  const float* grid = (const float*)d_in[1];
  const float* bw = (const float*)d_in[2];
  const float* sw = (const float*)d_in[3];
  const float* sc = (const float*)d_in[4];
  float* out = (float*)d_out;

  const size_t Bbytes = (size_t)OUT_F * KTOT * 2;   // 18.9 MB
  const size_t rowBytes = (size_t)KTOT * 2;         // 18 KB / A-row

  if (ws_size >= Bbytes + 256 * rowBytes) {
    __hip_bfloat16* Bp = (__hip_bfloat16*)d_ws;
    __hip_bfloat16* Ap = (__hip_bfloat16*)((char*)d_ws + Bbytes);
    size_t arows = (ws_size - Bbytes) / rowBytes;
    int chunk = (int)((arows / 256) * 256);
    if (chunk > M_ROWS) chunk = M_ROWS;

    pack_b<<<OUT_F * 128 / 256, 256, 0, stream>>>(bw, sw, sc, Bp);
    for (int r0 = 0; r0 < M_ROWS; r0 += chunk) {
      int rows = M_ROWS - r0 < chunk ? M_ROWS - r0 : chunk;   // multiple of 256
      expand_a<<<(rows / 16) * 8, 256, 0, stream>>>(x, grid, Ap, r0, rows);
      gemm_v9<<<(rows / BM) * 8, 512, 0, stream>>>(Ap, Bp, out + (size_t)r0 * OUT_F);
    }
  } else {
    kan_naive<<<M_ROWS, 256, 0, stream>>>(x, grid, bw, sw, sc, out);
  }
}

// Round 10
// 194.544 us; speedup vs baseline: 1.9413x; 1.1234x over previous
//
#include <hip/hip_runtime.h>
#include <hip/hip_bf16.h>

#define IN_F 1024
#define OUT_F 1024
#define KTOT (IN_F * 9)   // 9216: channel-major, k = c*1024 + i, c=0 is silu
#define M_ROWS 8192

#define BM 256
#define BN 128
#define BK 64
#define NT (KTOT / BK)    // 144 K-tiles

typedef short bf16x8 __attribute__((ext_vector_type(8)));
typedef int   i32x4  __attribute__((ext_vector_type(4)));
typedef float f32x4  __attribute__((ext_vector_type(4)));

#define AS1 __attribute__((address_space(1)))
#define AS3 __attribute__((address_space(3)))

// ---------------------------------------------------------------- basis eval
__device__ __forceinline__ void kan_basis_fast(
    float xv, const float* __restrict__ g,
    const float* __restrict__ inv1, const float* __restrict__ inv2,
    const float* __restrict__ inv3, float* __restrict__ out) {
  float b[11];
#pragma unroll
  for (int j = 0; j < 11; ++j)
    b[j] = (xv >= g[j] && xv < g[j + 1]) ? 1.0f : 0.0f;
#pragma unroll
  for (int j = 0; j < 10; ++j)
    b[j] = (xv - g[j]) * inv1[j] * b[j] + (g[j + 2] - xv) * inv1[j + 1] * b[j + 1];
#pragma unroll
  for (int j = 0; j < 9; ++j)
    b[j] = (xv - g[j]) * inv2[j] * b[j] + (g[j + 3] - xv) * inv2[j + 1] * b[j + 1];
#pragma unroll
  for (int j = 0; j < 8; ++j)
    b[j] = (xv - g[j]) * inv3[j] * b[j] + (g[j + 4] - xv) * inv3[j + 1] * b[j + 1];
#pragma unroll
  for (int j = 0; j < 8; ++j) out[j] = b[j];
}

// ------------------------------------------------- A expansion (fp32 -> bf16)
// Writes A in MFMA-FRAGMENT order: fragment (bm,kt,wm,m,kk) = contiguous 1 KB,
// element addr = lane*16B, lane = lhi*16 + l15  (A-operand: row=l15, k=lhi*8+j).
__global__ __launch_bounds__(256) void expand_a(
    const float* __restrict__ x, const float* __restrict__ grid,
    __hip_bfloat16* __restrict__ A, int row0, int nrows) {
  const int tid = threadIdx.x;
  const int lane = tid & 63;
  const int wvx = tid >> 6;            // 0..3 : i-subblock
  const int l15 = lane & 15;
  const int lhi = lane >> 4;

  const int nb = blockIdx.x >> 3;      // 16-row group (local)
  const int ib = blockIdx.x & 7;       // 128-wide i group
  const int n_l = nb * 16 + l15;       // local row
  const int i0 = ib * 128 + wvx * 32 + lhi * 8;

  const int bm = n_l >> 8, wm = (n_l >> 6) & 3, m = (n_l >> 4) & 3;

  float g[12];
  const float* gp = grid + (size_t)i0 * 12;   // rows identical by construction
#pragma unroll
  for (int j = 0; j < 12; ++j) g[j] = gp[j];
  float inv1[11], inv2[10], inv3[9];
#pragma unroll
  for (int j = 0; j < 11; ++j) inv1[j] = 1.0f / (g[j + 1] - g[j]);
#pragma unroll
  for (int j = 0; j < 10; ++j) inv2[j] = 1.0f / (g[j + 2] - g[j]);
#pragma unroll
  for (int j = 0; j < 9; ++j)  inv3[j] = 1.0f / (g[j + 3] - g[j]);

  const float* xp = x + (size_t)(row0 + n_l) * IN_F + i0;
  float xs[8];
  *(f32x4*)&xs[0] = *(const f32x4*)xp;
  *(f32x4*)&xs[4] = *(const f32x4*)(xp + 4);

  bf16x8 out[9];
#pragma unroll
  for (int j = 0; j < 8; ++j) {
    float xv = xs[j];
    float bas[8];
    kan_basis_fast(xv, g, inv1, inv2, inv3, bas);
    float s = xv / (1.0f + __expf(-xv));
    out[0][j] = (short)__bfloat16_as_ushort(__float2bfloat16(s));
#pragma unroll
    for (int c = 0; c < 8; ++c)
      out[c + 1][j] = (short)__bfloat16_as_ushort(__float2bfloat16(bas[c]));
  }

#pragma unroll
  for (int c = 0; c < 9; ++c) {
    int k0 = c * IN_F + i0;            // 8-aligned; 32-block uniform per wave
    int kt = k0 >> 6;
    int kk = (k0 >> 5) & 1;
    size_t frag = ((((size_t)bm * NT + kt) * 4 + wm) * 4 + m) * 2 + kk;
    *(bf16x8*)(A + frag * 512 + lane * 8) = out[c];
  }
}

// --------------------------------------------------- B packing (fp32 -> bf16)
__global__ __launch_bounds__(256) void pack_b(
    const float* __restrict__ bw, const float* __restrict__ sw,
    const float* __restrict__ sc, __hip_bfloat16* __restrict__ B) {
  int t = blockIdx.x * 256 + threadIdx.x;   // one per (o, i0/8): 1024*128
  if (t >= OUT_F * 128) return;
  int o = t >> 7;
  int i0 = (t & 127) * 8;

  float bwv[8], scv[8];
  const float* bp = bw + (size_t)o * IN_F + i0;
  const float* sp = sc + (size_t)o * IN_F + i0;
  *(f32x4*)&bwv[0] = *(const f32x4*)bp;
  *(f32x4*)&bwv[4] = *(const f32x4*)(bp + 4);
  *(f32x4*)&scv[0] = *(const f32x4*)sp;
  *(f32x4*)&scv[4] = *(const f32x4*)(sp + 4);

  bf16x8 out[9];
#pragma unroll
  for (int j = 0; j < 8; ++j) {
    out[0][j] = (short)__bfloat16_as_ushort(__float2bfloat16(bwv[j]));
    const float* swp = sw + ((size_t)o * IN_F + i0 + j) * 8;
    float swv[8];
    *(f32x4*)&swv[0] = *(const f32x4*)swp;
    *(f32x4*)&swv[4] = *(const f32x4*)(swp + 4);
#pragma unroll
    for (int c = 0; c < 8; ++c)
      out[c + 1][j] = (short)__bfloat16_as_ushort(__float2bfloat16(swv[c] * scv[j]));
  }
  __hip_bfloat16* dst = B + (size_t)o * KTOT + i0;
#pragma unroll
  for (int c = 0; c < 9; ++c)
    *(bf16x8*)(dst + (size_t)c * IN_F) = out[c];
}

// -------------------------------------------------------------- bf16 GEMM BT
// v10: A-frags DIRECT global->reg via asm volatile global_load_dwordx4
// (fragment-ordered A buffer; opaque asm forces live registers -> no v9
// compiler sinking/spill). B through the proven LDS path (3-slot ring, 48 KB,
// T2 swizzle, asm ds_read). Per tile: exactly 10 VM ops (2 B-DMA + 8 A-loads)
// -> one vmcnt(10) proves tile-t A + tile-t+1 B landed; one barrier/tile.
// Floors/CU/tile: vector 80 KB ~1250 cyc, MFMA 1242, LDS-B 80 KB ~941.

__device__ __forceinline__ void gld16(const __hip_bfloat16* g, __hip_bfloat16* l) {
  __builtin_amdgcn_global_load_lds((AS1 void*)g, (AS3 void*)l, 16, 0, 0);
}

__device__ __forceinline__ bf16x8 dsr128(uint32_t addr) {
  i32x4 r;
  asm volatile("ds_read_b128 %0, %1" : "=v"(r) : "v"(addr));
  return __builtin_bit_cast(bf16x8, r);
}

#define GLOADX4(dst, base, OFF)                                            \
  asm volatile("global_load_dwordx4 %0, %1, off offset:" #OFF              \
               : "=v"(dst) : "v"(base))

#define SB __builtin_amdgcn_sched_barrier(0)

#define READ_B(dB, slot, h) do {                                           \
    uint32_t bS_ = bBase + (uint32_t)(slot) * (BN * BK * 2);               \
    _Pragma("unroll")                                                      \
    for (int n_ = 0; n_ < 4; ++n_) dB[n_] = dsr128(bS_ + bOffB[h][n_]);    \
  } while (0)

// A(t+1): 8 coalesced 1KB frag loads; bases advance 32 KB/tile
#define A_LOAD(DST) do {                                                   \
    GLOADX4(DST[0][0], aB0, 0);    GLOADX4(DST[0][1], aB0, 1024);          \
    GLOADX4(DST[1][0], aB0, 2048); GLOADX4(DST[1][1], aB0, 3072);          \
    GLOADX4(DST[2][0], aB1, 0);    GLOADX4(DST[2][1], aB1, 1024);          \
    GLOADX4(DST[3][0], aB1, 2048); GLOADX4(DST[3][1], aB1, 3072);          \
    aB0 += 32768; aB1 += 32768;                                            \
  } while (0)

#define MFMA_K(CUR, H, BFR) do {                                           \
    __builtin_amdgcn_s_setprio(1);                                         \
    _Pragma("unroll")                                                      \
    for (int m_ = 0; m_ < 4; ++m_)                                         \
      _Pragma("unroll")                                                    \
      for (int n_ = 0; n_ < 4; ++n_)                                       \
        acc[m_][n_] = __builtin_amdgcn_mfma_f32_16x16x32_bf16(             \
            __builtin_bit_cast(bf16x8, CUR[m_][H]), BFR[n_],               \
            acc[m_][n_], 0, 0, 0);                                         \
    __builtin_amdgcn_s_setprio(0);                                         \
  } while (0)

#define STAGE_B(slot, koff) do {                                           \
    __hip_bfloat16* bsD_ = &Bs[slot][0];                                   \
    gld16(bSrc[0] + (koff), bsD_ + bDst[0]);                               \
    gld16(bSrc[1] + (koff), bsD_ + bDst[1]);                               \
  } while (0)

// steady tile t: issue {gb reads, B-stage(t+2), A-load(t+1)}; vmcnt(10)
// proves A(t) [11th..18th oldest] and B(t+1) [older still] landed.
// Barrier publishes slot t+1; slot overwrite (t+2 -> slot t-1) is safe since
// every wave's lgkm(0) on its t-1 reads preceded barrier(t-1), and stage is
// issued after this wave passed barrier(t-1).
#define TILE_FULL(CUR, NXT, KT2) do {                                      \
    const int nxt_ = cur == 2 ? 0 : cur + 1;                               \
    const int stg_ = cur == 0 ? 2 : cur - 1;                               \
    READ_B(gb, cur, 1);                                                    \
    STAGE_B(stg_, KT2);                                                    \
    A_LOAD(NXT);                                                           \
    SB;                                                                    \
    asm volatile("s_waitcnt lgkmcnt(4)" ::: "memory"); SB;                 \
    asm volatile("s_waitcnt vmcnt(10)" ::: "memory"); SB;                  \
    MFMA_K(CUR, 0, fb);                                                    \
    SB;                                                                    \
    asm volatile("s_waitcnt lgkmcnt(0)" ::: "memory"); SB;                 \
    __builtin_amdgcn_s_barrier(); SB;                                      \
    READ_B(fb, nxt_, 0);                                                   \
    SB;                                                                    \
    MFMA_K(CUR, 1, gb);                                                    \
    SB;                                                                    \
    cur = nxt_;                                                            \
  } while (0)

// t = NT-2: no B-stage; A-load for last tile; vmcnt(8) leaves only A(NT-1)
#define TILE_NT2(CUR, NXT) do {                                            \
    const int nxt_ = cur == 2 ? 0 : cur + 1;                               \
    READ_B(gb, cur, 1);                                                    \
    A_LOAD(NXT);                                                           \
    SB;                                                                    \
    asm volatile("s_waitcnt lgkmcnt(4)" ::: "memory"); SB;                 \
    asm volatile("s_waitcnt vmcnt(8)" ::: "memory"); SB;                   \
    MFMA_K(CUR, 0, fb);                                                    \
    SB;                                                                    \
    asm volatile("s_waitcnt lgkmcnt(0)" ::: "memory"); SB;                 \
    __builtin_amdgcn_s_barrier(); SB;                                      \
    READ_B(fb, nxt_, 0);                                                   \
    SB;                                                                    \
    MFMA_K(CUR, 1, gb);                                                    \
    SB;                                                                    \
    cur = nxt_;                                                            \
  } while (0)

#define TILE_LAST(CUR) do {                                                \
    READ_B(gb, cur, 1);                                                    \
    SB;                                                                    \
    asm volatile("s_waitcnt lgkmcnt(4)" ::: "memory"); SB;                 \
    asm volatile("s_waitcnt vmcnt(0)" ::: "memory"); SB;                   \
    MFMA_K(CUR, 0, fb);                                                    \
    SB;                                                                    \
    asm volatile("s_waitcnt lgkmcnt(0)" ::: "memory"); SB;                 \
    MFMA_K(CUR, 1, gb);                                                    \
    SB;                                                                    \
  } while (0)

__global__ __launch_bounds__(512, 2) void gemm_v10(
    const __hip_bfloat16* __restrict__ A, const __hip_bfloat16* __restrict__ B,
    float* __restrict__ C) {
  __shared__ __align__(16) __hip_bfloat16 Bs[3][BN * BK];  // 3 x 16 KB

  // T1 bijective XCD swizzle: 8 bn-blocks sharing an A-panel on one XCD
  const int nwg = gridDim.x;            // (M/256)*8, %8 == 0
  const int q = nwg >> 3;
  const int L = (blockIdx.x & 7) * q + (blockIdx.x >> 3);
  const int bm = L >> 3, bn = L & 7;

  const int tid = threadIdx.x;
  const int lane = tid & 63;
  const int wv = tid >> 6;            // 0..7
  const int wm = wv >> 1;             // 0..3 (64-row group)
  const int wn = wv & 1;              // 0..1 (64-col group)
  const int l15 = lane & 15, lhi = lane >> 4;
  const int K = KTOT;

  // ---- B staging: LDS linear, global source pre-swizzled (rule #21).
  const __hip_bfloat16* bSrc[2];
  int bDst[2];
#pragma unroll
  for (int j = 0; j < 2; ++j) {
    int p = j * 512 + wv * 64 + lane;
    int row = p >> 3;
    int col = (p & 7) ^ (row & 7);
    bSrc[j] = B + (size_t)(bn * BN + row) * K + col * 8;
    bDst[j] = (j * 512 + wv * 64) * 8;
  }

  // ---- B fragment read byte-offsets (swizzled), per kk half
  const uint32_t bBase = (uint32_t)(uintptr_t)(AS3 const void*)&Bs[0][0];
  uint32_t bOffB[2][4];
#pragma unroll
  for (int h = 0; h < 2; ++h)
#pragma unroll
    for (int n = 0; n < 4; ++n) {
      int rowB = wn * 64 + n * 16 + l15;
      bOffB[h][n] = (rowB * 64 + (((h * 4 + lhi) ^ (l15 & 7)) * 8)) * 2;
    }

  // ---- A: fragment-ordered panel; two byte-address bases, +32 KB per tile
  uint64_t aB0 = (uint64_t)(uintptr_t)(
      A + (size_t)bm * NT * 16384 + wm * 4096 + lane * 8);
  uint64_t aB1 = aB0 + 4096;

  f32x4 acc[4][4];
#pragma unroll
  for (int m = 0; m < 4; ++m)
#pragma unroll
    for (int n = 0; n < 4; ++n) acc[m][n] = f32x4{0.f, 0.f, 0.f, 0.f};

  i32x4 faR[4][2], gaR[4][2];    // A frags ping-pong (tile t / t+1)
  bf16x8 fb[4], gb[4];           // B frags kk0 / kk1

  // ---- prologue: stage B slots 0,1; load A(0); publish slot0
  STAGE_B(0, 0);                                      // vm 2
  STAGE_B(1, BK);                                     // vm 4
  A_LOAD(faR);                                        // vm 12
  asm volatile("s_waitcnt vmcnt(8)" ::: "memory");    // B slots landed
  SB;
  __builtin_amdgcn_s_barrier();
  SB;
  READ_B(fb, 0, 0);                                   // lgkm 4
  SB;

  int cur = 0;
  int kt2 = 2 * BK;
#pragma unroll 1
  for (int tt = 0; tt < (NT - 2) / 2; ++tt) {         // 71 x 2 tiles
    TILE_FULL(faR, gaR, kt2); kt2 += BK;
    TILE_FULL(gaR, faR, kt2); kt2 += BK;
  }
  TILE_NT2(faR, gaR);                                 // t = 142
  TILE_LAST(gaR);                                     // t = 143

  // epilogue: C/D mapping col = lane&15, row = (lane>>4)*4 + reg [m89]
#pragma unroll
  for (int m = 0; m < 4; ++m)
#pragma unroll
    for (int n = 0; n < 4; ++n) {
      int col = bn * BN + wn * 64 + n * 16 + l15;
      int row0 = bm * BM + wm * 64 + m * 16 + lhi * 4;
#pragma unroll
      for (int j = 0; j < 4; ++j)
        C[(size_t)(row0 + j) * OUT_F + col] = acc[m][n][j];
    }
}

// ------------------------------------------------ naive fallback (insurance)
__global__ __launch_bounds__(256) void kan_naive(
    const float* __restrict__ x, const float* __restrict__ grid,
    const float* __restrict__ bw, const float* __restrict__ sw,
    const float* __restrict__ sc, float* __restrict__ out) {
  __shared__ float s_act[IN_F];
  __shared__ float s_bas[IN_F * 8];
  int n = blockIdx.x;
  for (int i = threadIdx.x; i < IN_F; i += 256) {
    float xv = x[(size_t)n * IN_F + i];
    float g[12];
    const float* gp = grid + i * 12;
#pragma unroll
    for (int t = 0; t < 12; ++t) g[t] = gp[t];
    float b[11];
#pragma unroll
    for (int j = 0; j < 11; ++j)
      b[j] = (xv >= g[j] && xv < g[j + 1]) ? 1.0f : 0.0f;
#pragma unroll
    for (int k = 1; k <= 3; ++k)
#pragma unroll
      for (int j = 0; j < 11 - k; ++j) {
        float left = (xv - g[j]) / (g[j + k] - g[j]);
        float right = (g[j + k + 1] - xv) / (g[j + k + 1] - g[j + 1]);
        b[j] = left * b[j] + right * b[j + 1];
      }
    s_act[i] = xv / (1.0f + __expf(-xv));
#pragma unroll
    for (int c = 0; c < 8; ++c) s_bas[i * 8 + c] = b[c];
  }
  __syncthreads();
  for (int o = threadIdx.x; o < OUT_F; o += 256) {
    float acc = 0.f;
    const float* bwo = bw + (size_t)o * IN_F;
    const float* swo = sw + (size_t)o * IN_F * 8;
    const float* sco = sc + (size_t)o * IN_F;
    for (int i = 0; i < IN_F; ++i) {
      acc += s_act[i] * bwo[i];
      float p = 0.f;
#pragma unroll
      for (int c = 0; c < 8; ++c) p += s_bas[i * 8 + c] * swo[i * 8 + c];
      acc += p * sco[i];
    }
    out[(size_t)n * OUT_F + o] = acc;
  }
}

// ---------------------------------------------------------------- launch
extern "C" void kernel_launch(void* const* d_in, const int* in_sizes, int n_in,
                              void* d_out, int out_size, void* d_ws, size_t ws_size,
                              hipStream_t stream) {
  const float* x  = (const float*)d_in[0];
  const float* grid = (const float*)d_in[1];
  const float* bw = (const float*)d_in[2];
  const float* sw = (const float*)d_in[3];
  const float* sc = (const float*)d_in[4];
  float* out = (float*)d_out;

  const size_t Bbytes = (size_t)OUT_F * KTOT * 2;   // 18.9 MB
  const size_t rowBytes = (size_t)KTOT * 2;         // 18 KB / A-row

  if (ws_size >= Bbytes + 256 * rowBytes) {
    __hip_bfloat16* Bp = (__hip_bfloat16*)d_ws;
    __hip_bfloat16* Ap = (__hip_bfloat16*)((char*)d_ws + Bbytes);
    size_t arows = (ws_size - Bbytes) / rowBytes;
    int chunk = (int)((arows / 256) * 256);
    if (chunk > M_ROWS) chunk = M_ROWS;

    pack_b<<<OUT_F * 128 / 256, 256, 0, stream>>>(bw, sw, sc, Bp);
    for (int r0 = 0; r0 < M_ROWS; r0 += chunk) {
      int rows = M_ROWS - r0 < chunk ? M_ROWS - r0 : chunk;   // multiple of 256
      expand_a<<<(rows / 16) * 8, 256, 0, stream>>>(x, grid, Ap, r0, rows);
      gemm_v10<<<(rows / BM) * 8, 512, 0, stream>>>(Ap, Bp, out + (size_t)r0 * OUT_F);
    }
  } else {
    kan_naive<<<M_ROWS, 256, 0, stream>>>(x, grid, bw, sw, sc, out);
  }
}

// Round 11
// 183.411 us; speedup vs baseline: 2.0591x; 1.0607x over previous
//
#include <hip/hip_runtime.h>
#include <hip/hip_bf16.h>

#define IN_F 1024
#define OUT_F 1024
#define KTOT (IN_F * 9)   // 9216: channel-major, k = c*1024 + i, c=0 is silu
#define M_ROWS 8192

#define BM 256
#define BN 128
#define BK 64
#define NT (KTOT / BK)    // 144 K-tiles

// frag-ordered buffers: A tile (bm,kt) = 32 contiguous KB (32 frags of 1 KB:
// [wm][m][kk]); B tile (bn,kt) = 16 contiguous KB (16 frags: [colg][kk]).
// Within a frag, lane = lhi*16+l15 holds 16 B: row/col = l15-group, k = lhi*8+j.
#define A_TILE_E 16384    // elements per A K-tile (32 KB)
#define B_TILE_E 8192     // elements per B K-tile (16 KB)

typedef short bf16x8 __attribute__((ext_vector_type(8)));
typedef int   i32x4  __attribute__((ext_vector_type(4)));
typedef float f32x4  __attribute__((ext_vector_type(4)));

#define AS1 __attribute__((address_space(1)))
#define AS3 __attribute__((address_space(3)))

// ---------------------------------------------------------------- basis eval
__device__ __forceinline__ void kan_basis_fast(
    float xv, const float* __restrict__ g,
    const float* __restrict__ inv1, const float* __restrict__ inv2,
    const float* __restrict__ inv3, float* __restrict__ out) {
  float b[11];
#pragma unroll
  for (int j = 0; j < 11; ++j)
    b[j] = (xv >= g[j] && xv < g[j + 1]) ? 1.0f : 0.0f;
#pragma unroll
  for (int j = 0; j < 10; ++j)
    b[j] = (xv - g[j]) * inv1[j] * b[j] + (g[j + 2] - xv) * inv1[j + 1] * b[j + 1];
#pragma unroll
  for (int j = 0; j < 9; ++j)
    b[j] = (xv - g[j]) * inv2[j] * b[j] + (g[j + 3] - xv) * inv2[j + 1] * b[j + 1];
#pragma unroll
  for (int j = 0; j < 8; ++j)
    b[j] = (xv - g[j]) * inv3[j] * b[j] + (g[j + 4] - xv) * inv3[j + 1] * b[j + 1];
#pragma unroll
  for (int j = 0; j < 8; ++j) out[j] = b[j];
}

// ------------------------------------------------- A expansion (fp32 -> bf16)
// Frag-ordered A (verified R9/R10): frag = (((bm*NT+kt)*4+wm)*4+m)*2+kk,
// lane = lhi*16+l15 holds A[row=...+l15][k=kt*64+kk*32+lhi*8+j]. Each wave
// store per channel c is one contiguous 1 KB fragment write.
__global__ __launch_bounds__(256) void expand_a(
    const float* __restrict__ x, const float* __restrict__ grid,
    __hip_bfloat16* __restrict__ A, int row0, int nrows) {
  const int tid = threadIdx.x;
  const int lane = tid & 63;
  const int wvx = tid >> 6;            // 0..3 : i-subblock
  const int l15 = lane & 15;
  const int lhi = lane >> 4;

  const int nb = blockIdx.x >> 3;      // 16-row group (local)
  const int ib = blockIdx.x & 7;       // 128-wide i group
  const int n_l = nb * 16 + l15;       // local row
  const int i0 = ib * 128 + wvx * 32 + lhi * 8;

  const int bm = n_l >> 8, wm = (n_l >> 6) & 3, m = (n_l >> 4) & 3;

  float g[12];
  const float* gp = grid + (size_t)i0 * 12;   // rows identical by construction
#pragma unroll
  for (int j = 0; j < 12; ++j) g[j] = gp[j];
  float inv1[11], inv2[10], inv3[9];
#pragma unroll
  for (int j = 0; j < 11; ++j) inv1[j] = 1.0f / (g[j + 1] - g[j]);
#pragma unroll
  for (int j = 0; j < 10; ++j) inv2[j] = 1.0f / (g[j + 2] - g[j]);
#pragma unroll
  for (int j = 0; j < 9; ++j)  inv3[j] = 1.0f / (g[j + 3] - g[j]);

  const float* xp = x + (size_t)(row0 + n_l) * IN_F + i0;
  float xs[8];
  *(f32x4*)&xs[0] = *(const f32x4*)xp;
  *(f32x4*)&xs[4] = *(const f32x4*)(xp + 4);

  bf16x8 out[9];
#pragma unroll
  for (int j = 0; j < 8; ++j) {
    float xv = xs[j];
    float bas[8];
    kan_basis_fast(xv, g, inv1, inv2, inv3, bas);
    float s = xv / (1.0f + __expf(-xv));
    out[0][j] = (short)__bfloat16_as_ushort(__float2bfloat16(s));
#pragma unroll
    for (int c = 0; c < 8; ++c)
      out[c + 1][j] = (short)__bfloat16_as_ushort(__float2bfloat16(bas[c]));
  }

#pragma unroll
  for (int c = 0; c < 9; ++c) {
    int k0 = c * IN_F + i0;            // wave-uniform kt,kk per c
    int kt = k0 >> 6;
    int kk = (k0 >> 5) & 1;
    size_t frag = ((((size_t)bm * NT + kt) * 4 + wm) * 4 + m) * 2 + kk;
    *(bf16x8*)(A + frag * 512 + lane * 8) = out[c];
  }
}

// --------------------------------------------------- B packing (fp32 -> bf16)
// Frag-ordered B: frag = ((bn*NT+kt)*8+colg)*2+kk, lane = lhi*16+l15 holds
// B[col=colg*16+l15][k=kt*64+kk*32+lhi*8+j]. Wave = (o-group 16, k-block 32):
// each per-channel store is one contiguous 1 KB fragment write.
__global__ __launch_bounds__(256) void pack_b(
    const float* __restrict__ bw, const float* __restrict__ sw,
    const float* __restrict__ sc, __hip_bfloat16* __restrict__ B) {
  const int tid = threadIdx.x;
  const int lane = tid & 63;
  const int wid = blockIdx.x * 4 + (tid >> 6);   // 0..2047
  const int og = wid >> 5;           // 0..63: o-group of 16
  const int ib32 = wid & 31;         // 0..31: 32-wide i block
  const int bn = og >> 3, colg = og & 7;
  const int l15 = lane & 15, lhi = lane >> 4;
  const int o = og * 16 + l15;
  const int i0 = ib32 * 32 + lhi * 8;

  float bwv[8], scv[8];
  const float* bp = bw + (size_t)o * IN_F + i0;
  const float* sp = sc + (size_t)o * IN_F + i0;
  *(f32x4*)&bwv[0] = *(const f32x4*)bp;
  *(f32x4*)&bwv[4] = *(const f32x4*)(bp + 4);
  *(f32x4*)&scv[0] = *(const f32x4*)sp;
  *(f32x4*)&scv[4] = *(const f32x4*)(sp + 4);

  bf16x8 out[9];
#pragma unroll
  for (int j = 0; j < 8; ++j) {
    out[0][j] = (short)__bfloat16_as_ushort(__float2bfloat16(bwv[j]));
    const float* swp = sw + ((size_t)o * IN_F + i0 + j) * 8;
    float swv[8];
    *(f32x4*)&swv[0] = *(const f32x4*)swp;
    *(f32x4*)&swv[4] = *(const f32x4*)(swp + 4);
#pragma unroll
    for (int c = 0; c < 8; ++c)
      out[c + 1][j] = (short)__bfloat16_as_ushort(__float2bfloat16(swv[c] * scv[j]));
  }

#pragma unroll
  for (int c = 0; c < 9; ++c) {
    int kt = c * 16 + (ib32 >> 1);     // k0 = c*1024 + ib32*32
    int kk = ib32 & 1;
    size_t frag = ((size_t)bn * NT + kt) * 16 + colg * 2 + kk;
    *(bf16x8*)(B + frag * 512 + lane * 8) = out[c];
  }
}

// -------------------------------------------------------------- bf16 GEMM BT
// v11 = v7's proven schedule (3-slot ring staged 2 ahead, 6 DMA/tile,
// vmcnt(6), lgkm 8/0, ONE barrier/tile, reg-level frag double-buffer) over
// FRAG-ORDERED A and B: staging = contiguous 1 KB wave-ops, linear LDS, NO
// swizzle; every ds_read_b128 = frag_base + lane*16 (canonical even pattern).

__device__ __forceinline__ void gld16(const __hip_bfloat16* g, __hip_bfloat16* l) {
  __builtin_amdgcn_global_load_lds((AS1 void*)g, (AS3 void*)l, 16, 0, 0);
}

// inline-asm LDS read: opaque to alias analysis -> no compiler vmcnt(0) drain
__device__ __forceinline__ bf16x8 dsr128(uint32_t addr) {
  i32x4 r;
  asm volatile("ds_read_b128 %0, %1" : "=v"(r) : "v"(addr));
  return __builtin_bit_cast(bf16x8, r);
}

#define SB __builtin_amdgcn_sched_barrier(0)

#define SLOT_B 49152   // bytes per LDS slot (A 32K + B 16K)
#define SLOT_E 24576   // elements per LDS slot

#define READ_FRAGS(dA, dB, slot, h) do {                                   \
    uint32_t s_ = ldsB + (uint32_t)(slot) * SLOT_B;                        \
    _Pragma("unroll")                                                      \
    for (int m_ = 0; m_ < 4; ++m_) dA[m_] = dsr128(s_ + aOff[h][m_]);      \
    _Pragma("unroll")                                                      \
    for (int n_ = 0; n_ < 4; ++n_) dB[n_] = dsr128(s_ + bOff[h][n_]);      \
  } while (0)

#define MFMA_BURST(sA, sB) do {                                            \
    __builtin_amdgcn_s_setprio(1);                                         \
    _Pragma("unroll")                                                      \
    for (int m_ = 0; m_ < 4; ++m_)                                         \
      _Pragma("unroll")                                                    \
      for (int n_ = 0; n_ < 4; ++n_)                                       \
        acc[m_][n_] = __builtin_amdgcn_mfma_f32_16x16x32_bf16(             \
            sA[m_], sB[n_], acc[m_][n_], 0, 0, 0);                         \
    __builtin_amdgcn_s_setprio(0);                                         \
  } while (0)

// stage tile t into slot: 4 A wave-ops + 2 B wave-ops, all 1 KB contiguous
#define STAGE_T(slot, t) do {                                              \
    __hip_bfloat16* d_ = ldsP + (slot) * SLOT_E;                           \
    const __hip_bfloat16* aT_ = aG + (size_t)(t) * A_TILE_E;               \
    const __hip_bfloat16* bT_ = bG + (size_t)(t) * B_TILE_E;               \
    gld16(aT_,         d_ + dstE);                                         \
    gld16(aT_ + 4096,  d_ + dstE + 4096);                                  \
    gld16(aT_ + 8192,  d_ + dstE + 8192);                                  \
    gld16(aT_ + 12288, d_ + dstE + 12288);                                 \
    gld16(bT_,         d_ + 16384 + dstE);                                 \
    gld16(bT_ + 4096,  d_ + 16384 + dstE + 4096);                          \
  } while (0)

#define TILE_FULL(t) do {                                                  \
    const int nxt_ = cur == 2 ? 0 : cur + 1;                               \
    const int stg_ = cur == 0 ? 2 : cur - 1;                               \
    READ_FRAGS(ga, gb, cur, 1);                      /* lgkm 16 */         \
    STAGE_T(stg_, (t) + 2);                          /* vm -> 12 */        \
    SB;                                                                    \
    asm volatile("s_waitcnt lgkmcnt(8)" ::: "memory"); SB;                 \
    MFMA_BURST(fa, fb);                                                    \
    SB;                                                                    \
    asm volatile("s_waitcnt lgkmcnt(0)" ::: "memory"); SB;                 \
    asm volatile("s_waitcnt vmcnt(6)" ::: "memory"); SB;                   \
    __builtin_amdgcn_s_barrier(); SB;                /* publish t+1 */     \
    READ_FRAGS(fa, fb, nxt_, 0);                     /* lgkm 8 */          \
    SB;                                                                    \
    MFMA_BURST(ga, gb);                                                    \
    SB;                                                                    \
    cur = nxt_;                                                            \
  } while (0)

#define TILE_NT2() do {                                                    \
    const int nxt_ = cur == 2 ? 0 : cur + 1;                               \
    READ_FRAGS(ga, gb, cur, 1);                                            \
    SB;                                                                    \
    asm volatile("s_waitcnt lgkmcnt(8)" ::: "memory"); SB;                 \
    MFMA_BURST(fa, fb);                                                    \
    SB;                                                                    \
    asm volatile("s_waitcnt lgkmcnt(0)" ::: "memory"); SB;                 \
    asm volatile("s_waitcnt vmcnt(0)" ::: "memory"); SB;                   \
    __builtin_amdgcn_s_barrier(); SB;                                      \
    READ_FRAGS(fa, fb, nxt_, 0);                                           \
    SB;                                                                    \
    MFMA_BURST(ga, gb);                                                    \
    SB;                                                                    \
    cur = nxt_;                                                            \
  } while (0)

#define TILE_LAST() do {                                                   \
    READ_FRAGS(ga, gb, cur, 1);                                            \
    SB;                                                                    \
    asm volatile("s_waitcnt lgkmcnt(8)" ::: "memory"); SB;                 \
    MFMA_BURST(fa, fb);                                                    \
    SB;                                                                    \
    asm volatile("s_waitcnt lgkmcnt(0)" ::: "memory"); SB;                 \
    MFMA_BURST(ga, gb);                                                    \
    SB;                                                                    \
  } while (0)

__global__ __launch_bounds__(512, 2) void gemm_v11(
    const __hip_bfloat16* __restrict__ A, const __hip_bfloat16* __restrict__ B,
    float* __restrict__ C) {
  __shared__ __align__(16) __hip_bfloat16 S[3][SLOT_E];  // 3 x (A 32K | B 16K)

  // T1 bijective XCD swizzle: 8 bn-blocks sharing an A-panel on one XCD
  const int nwg = gridDim.x;            // (M/256)*8, %8 == 0
  const int q = nwg >> 3;
  const int L = (blockIdx.x & 7) * q + (blockIdx.x >> 3);
  const int bm = L >> 3, bn = L & 7;

  const int tid = threadIdx.x;
  const int lane = tid & 63;
  const int wv = tid >> 6;            // 0..7
  const int wm = wv >> 1;             // 0..3 (64-row group)
  const int wn = wv & 1;              // 0..1 (64-col group)
  const int l15 = lane & 15, lhi = lane >> 4;

  // ---- staging bases: contiguous per-tile panels, per-lane 16 B
  const __hip_bfloat16* aG = A + (size_t)bm * NT * A_TILE_E + (wv * 64 + lane) * 8;
  const __hip_bfloat16* bG = B + (size_t)bn * NT * B_TILE_E + (wv * 64 + lane) * 8;
  __hip_bfloat16* ldsP = &S[0][0];
  const int dstE = wv * 512;          // wave's element offset within a 4096-chunk

  // ---- fragment read byte-offsets: frag_idx*1024 + lane*16
  const uint32_t ldsB = (uint32_t)(uintptr_t)(AS3 const void*)&S[0][0];
  uint32_t aOff[2][4], bOff[2][4];
#pragma unroll
  for (int h = 0; h < 2; ++h)
#pragma unroll
    for (int m = 0; m < 4; ++m) {
      aOff[h][m] = (uint32_t)((wm * 8 + m * 2 + h) * 1024 + lane * 16);
      bOff[h][m] = (uint32_t)(32768 + ((wn * 4 + m) * 2 + h) * 1024 + lane * 16);
    }

  f32x4 acc[4][4];
#pragma unroll
  for (int m = 0; m < 4; ++m)
#pragma unroll
    for (int n = 0; n < 4; ++n) acc[m][n] = f32x4{0.f, 0.f, 0.f, 0.f};

  bf16x8 fa[4], fb[4];   // kk0 frags (preloaded)
  bf16x8 ga[4], gb[4];   // kk1 frags

  // ---- prologue: stage tiles 0,1; publish slot0; preload kk0(0)
  STAGE_T(0, 0);
  STAGE_T(1, 1);
  asm volatile("s_waitcnt vmcnt(6)" ::: "memory");   // tile 0 landed
  SB;
  __builtin_amdgcn_s_barrier();
  SB;
  READ_FRAGS(fa, fb, 0, 0);                          // lgkm 8
  SB;

  int cur = 0;
  for (int t = 0; t < NT - 2; ++t) TILE_FULL(t);
  TILE_NT2();                                        // t = NT-2
  TILE_LAST();                                       // t = NT-1

  // epilogue: C/D mapping col = lane&15, row = (lane>>4)*4 + reg [m89]
#pragma unroll
  for (int m = 0; m < 4; ++m)
#pragma unroll
    for (int n = 0; n < 4; ++n) {
      int col = bn * BN + wn * 64 + n * 16 + l15;
      int row0 = bm * BM + wm * 64 + m * 16 + lhi * 4;
#pragma unroll
      for (int j = 0; j < 4; ++j)
        C[(size_t)(row0 + j) * OUT_F + col] = acc[m][n][j];
    }
}

// ------------------------------------------------ naive fallback (insurance)
__global__ __launch_bounds__(256) void kan_naive(
    const float* __restrict__ x, const float* __restrict__ grid,
    const float* __restrict__ bw, const float* __restrict__ sw,
    const float* __restrict__ sc, float* __restrict__ out) {
  __shared__ float s_act[IN_F];
  __shared__ float s_bas[IN_F * 8];
  int n = blockIdx.x;
  for (int i = threadIdx.x; i < IN_F; i += 256) {
    float xv = x[(size_t)n * IN_F + i];
    float g[12];
    const float* gp = grid + i * 12;
#pragma unroll
    for (int t = 0; t < 12; ++t) g[t] = gp[t];
    float b[11];
#pragma unroll
    for (int j = 0; j < 11; ++j)
      b[j] = (xv >= g[j] && xv < g[j + 1]) ? 1.0f : 0.0f;
#pragma unroll
    for (int k = 1; k <= 3; ++k)
#pragma unroll
      for (int j = 0; j < 11 - k; ++j) {
        float left = (xv - g[j]) / (g[j + k] - g[j]);
        float right = (g[j + k + 1] - xv) / (g[j + k + 1] - g[j + 1]);
        b[j] = left * b[j] + right * b[j + 1];
      }
    s_act[i] = xv / (1.0f + __expf(-xv));
#pragma unroll
    for (int c = 0; c < 8; ++c) s_bas[i * 8 + c] = b[c];
  }
  __syncthreads();
  for (int o = threadIdx.x; o < OUT_F; o += 256) {
    float acc = 0.f;
    const float* bwo = bw + (size_t)o * IN_F;
    const float* swo = sw + (size_t)o * IN_F * 8;
    const float* sco = sc + (size_t)o * IN_F;
    for (int i = 0; i < IN_F; ++i) {
      acc += s_act[i] * bwo[i];
      float p = 0.f;
#pragma unroll
      for (int c = 0; c < 8; ++c) p += s_bas[i * 8 + c] * swo[i * 8 + c];
      acc += p * sco[i];
    }
    out[(size_t)n * OUT_F + o] = acc;
  }
}

// ---------------------------------------------------------------- launch
extern "C" void kernel_launch(void* const* d_in, const int* in_sizes, int n_in,
                              void* d_out, int out_size, void* d_ws, size_t ws_size,
                              hipStream_t stream) {
  const float* x  = (const float*)d_in[0];
  const float* grid = (const float*)d_in[1];
  const float* bw = (const float*)d_in[2];
  const float* sw = (const float*)d_in[3];
  const float* sc = (const float*)d_in[4];
  float* out = (float*)d_out;

  const size_t Bbytes = (size_t)OUT_F * KTOT * 2;   // 18.9 MB
  const size_t rowBytes = (size_t)KTOT * 2;         // 18 KB / A-row

  if (ws_size >= Bbytes + 256 * rowBytes) {
    __hip_bfloat16* Bp = (__hip_bfloat16*)d_ws;
    __hip_bfloat16* Ap = (__hip_bfloat16*)((char*)d_ws + Bbytes);
    size_t arows = (ws_size - Bbytes) / rowBytes;
    int chunk = (int)((arows / 256) * 256);
    if (chunk > M_ROWS) chunk = M_ROWS;

    pack_b<<<OUT_F * 128 / 256, 256, 0, stream>>>(bw, sw, sc, Bp);
    for (int r0 = 0; r0 < M_ROWS; r0 += chunk) {
      int rows = M_ROWS - r0 < chunk ? M_ROWS - r0 : chunk;   // multiple of 256
      expand_a<<<(rows / 16) * 8, 256, 0, stream>>>(x, grid, Ap, r0, rows);
      gemm_v11<<<(rows / BM) * 8, 512, 0, stream>>>(Ap, Bp, out + (size_t)r0 * OUT_F);
    }
  } else {
    kan_naive<<<M_ROWS, 256, 0, stream>>>(x, grid, bw, sw, sc, out);
  }
}